// Round 1
// baseline (465.821 us; speedup 1.0000x reference)
//
#include <hip/hip_runtime.h>

typedef __attribute__((ext_vector_type(8))) short shortx8;
typedef __attribute__((ext_vector_type(4))) float floatx4;
typedef unsigned short u16;
typedef unsigned int u32;

__device__ __forceinline__ float bf2f(unsigned short u) {
    union { unsigned int i; float f; } v; v.i = ((unsigned int)u) << 16; return v.f;
}
__device__ __forceinline__ float bfl(u32 u) {
    union { u32 i; float f; } v; v.i = u << 16; return v.f;
}
__device__ __forceinline__ float bfh(u32 u) {
    union { u32 i; float f; } v; v.i = u & 0xFFFF0000u; return v.f;
}
__device__ __forceinline__ unsigned short f2bf(float f) {
    union { float f; unsigned int i; } v; v.f = f;
    unsigned int x = v.i;
    unsigned int r = x + 0x7FFFu + ((x >> 16) & 1u);
    return (unsigned short)(r >> 16);
}
__device__ __forceinline__ float ldf(const void* p, int i, bool f32) {
    return f32 ? ((const float*)p)[i] : bf2f(((const u16*)p)[i]);
}

// ---------------------------------------------------------------------------
// Block 0: storage-format detection (flags[0]: floats fp32; flags[1]: idx
// int64). Blocks 1..: zero the degree array.
// ---------------------------------------------------------------------------
__global__ __launch_bounds__(256) void detect_zero_k(
    const u16* __restrict__ nf, const int* __restrict__ ei,
    int* __restrict__ flags, int* __restrict__ deg, int M)
{
    int tid = threadIdx.x;
    if (blockIdx.x != 0) {
        int i = (blockIdx.x - 1) * 256 + tid;
        if (i < M) deg[i] = 0;
        return;
    }
    __shared__ int cnt[2];
    if (tid < 2) cnt[tid] = 0;
    __syncthreads();
    int c0 = 0;
    for (int i = tid; i < 65536; i += 256) {
        u16 v = nf[i];
        if ((v & 0x7F80u) == 0x7F80u) c0++;
    }
    int c1 = 0;
    for (int i = tid; i < 4096; i += 256) {
        if (ei[2 * i + 1] != 0) c1++;
    }
    atomicAdd(&cnt[0], c0);
    atomicAdd(&cnt[1], c1);
    __syncthreads();
    if (tid == 0) {
        flags[0] = (cnt[0] > 8) ? 1 : 0;
        flags[1] = (cnt[1] < 100) ? 1 : 0;
    }
}

// ---------------------------------------------------------------------------
// Prep: W -> MFMA B-fragment order (bf16); biases/We/be -> fp32 workspace.
// ---------------------------------------------------------------------------
__global__ __launch_bounds__(256) void prep_k(
    const void* __restrict__ W0, const void* __restrict__ W1,
    const void* __restrict__ W2, const void* __restrict__ W3,
    const void* __restrict__ b0, const void* __restrict__ b1,
    const void* __restrict__ b2, const void* __restrict__ b3,
    const void* __restrict__ We, const void* __restrict__ be,
    const int* __restrict__ flags,
    u16* __restrict__ WT, float* __restrict__ biasWs,
    float* __restrict__ WeWs, float* __restrict__ beWs)
{
    bool f32 = flags[0] != 0;
    int tid = threadIdx.x;
    if (blockIdx.x < 32) {
        int t = blockIdx.x * 256 + tid;
        int mat  = t >> 11;
        int r    = t & 2047;
        int lane = r & 63;
        int ks   = (r >> 6) & 3;
        int ct   = r >> 8;
        const void* W = (mat == 0) ? W0 : (mat == 1) ? W1 : (mat == 2) ? W2 : W3;
        int k0  = ks * 32 + (lane >> 4) * 8;
        int col = ct * 16 + (lane & 15);
        u16 tmp[8];
#pragma unroll
        for (int j = 0; j < 8; ++j) {
            int off = (k0 + j) * 128 + col;
            tmp[j] = f32 ? f2bf(((const float*)W)[off]) : ((const u16*)W)[off];
        }
        *(shortx8*)(WT + (size_t)t * 8) = *(const shortx8*)tmp;
    } else {
        if (tid < 128) {
            biasWs[0 * 128 + tid] = ldf(b0, tid, f32);
            biasWs[1 * 128 + tid] = ldf(b1, tid, f32);
            biasWs[2 * 128 + tid] = ldf(b2, tid, f32);
            biasWs[3 * 128 + tid] = ldf(b3, tid, f32);
        }
        WeWs[tid] = ldf(We, tid, f32);
        if (tid < 8) beWs[tid] = ldf(be, tid, f32);
    }
}

// ---------------------------------------------------------------------------
// Pass 1 over edges: degree histogram only (CSR slot assignment moved to the
// scatter pass via an atomic cursor -> no rank array needed at all).
// ---------------------------------------------------------------------------
__global__ __launch_bounds__(256) void hist_k(
    const int* __restrict__ ei, int* __restrict__ deg,
    int E, const int* __restrict__ flags)
{
    int e = blockIdx.x * 256 + threadIdx.x;
    if (e >= E) return;
    int tgt = flags[1] ? ei[2 * (E + e)] : ei[E + e];
    atomicAdd(&deg[tgt], 1);
}

// ---------------------------------------------------------------------------
// Parallel scan (3 tiny kernels): deg -> rowptr (exclusive).
// scan1: per-block inclusive scan; scan2: block-sum exclusive scan;
// scan3: rowptr[i+1] = incl[i] + boff[block(i)], rowptr[0] = 0, and
//        cur[i] = rowptr[i] written IN PLACE over incl (scatter cursor).
// ---------------------------------------------------------------------------
__global__ __launch_bounds__(256) void scan1_k(
    const int* __restrict__ deg, int* __restrict__ incl, int* __restrict__ bsum, int M)
{
    __shared__ int s[256];
    int tid = threadIdx.x;
    int i = blockIdx.x * 256 + tid;
    int v = (i < M) ? deg[i] : 0;
    s[tid] = v;
    __syncthreads();
#pragma unroll
    for (int off = 1; off < 256; off <<= 1) {
        int t = (tid >= off) ? s[tid - off] : 0;
        __syncthreads();
        s[tid] += t;
        __syncthreads();
    }
    if (i < M) incl[i] = s[tid];
    if (tid == 255) bsum[blockIdx.x] = s[255];
}

__global__ __launch_bounds__(256) void scan2_k(
    const int* __restrict__ bsum, int* __restrict__ boff, int nb)
{
    __shared__ int s[256];
    int tid = threadIdx.x;
    int v = (tid < nb) ? bsum[tid] : 0;
    s[tid] = v;
    __syncthreads();
#pragma unroll
    for (int off = 1; off < 256; off <<= 1) {
        int t = (tid >= off) ? s[tid - off] : 0;
        __syncthreads();
        s[tid] += t;
        __syncthreads();
    }
    if (tid < nb) boff[tid] = s[tid] - v;   // exclusive
}

__global__ __launch_bounds__(256) void scan3_k(
    int* __restrict__ incl_cur, const int* __restrict__ boff,
    const int* __restrict__ deg, int* __restrict__ rowptr, int M)
{
    int i = blockIdx.x * 256 + threadIdx.x;
    if (i >= M) return;
    int r = incl_cur[i] + boff[i >> 8];
    rowptr[i + 1] = r;
    incl_cur[i] = r - deg[i];   // cur[i] = rowptr[i]  (in place, own slot only)
    if (i == 0) rowptr[0] = 0;
}

// ---------------------------------------------------------------------------
// Fused QKV GEMM: A fragments loaded once, 3 weight matrices applied.
// Q -> Qb (stride 128); K,V -> interleaved KVb (node n: [K row | V row],
// 512 B per node) so node_agg gathers ONE contiguous region per edge.
// ---------------------------------------------------------------------------
__global__ __launch_bounds__(256) void qkv_gemm_k(
    const void* __restrict__ A, int M,
    const u16* __restrict__ WT, const float* __restrict__ biasWs,
    u16* __restrict__ Qb, u16* __restrict__ KVb,
    const int* __restrict__ flags)
{
    bool aF32 = flags[0] != 0;
    int lane = threadIdx.x & 63;
    int wave = threadIdx.x >> 6;
    int quad = lane >> 4;
    int l15  = lane & 15;
    int m0   = blockIdx.x * 128 + wave * 32;

    shortx8 afrag[2][4];
#pragma unroll
    for (int mt = 0; mt < 2; ++mt) {
        int row = m0 + mt * 16 + l15;
        row = row < M ? row : M - 1;
#pragma unroll
        for (int ks = 0; ks < 4; ++ks) {
            size_t base = (size_t)row * 128 + ks * 32 + quad * 8;
            if (aF32) {
                const floatx4* ap = (const floatx4*)((const float*)A + base);
                floatx4 f0 = ap[0], f1 = ap[1];
                u16 tmp[8];
#pragma unroll
                for (int j = 0; j < 4; ++j) { tmp[j] = f2bf(f0[j]); tmp[4 + j] = f2bf(f1[j]); }
                afrag[mt][ks] = *(const shortx8*)tmp;
            } else {
                afrag[mt][ks] = *(const shortx8*)((const u16*)A + base);
            }
        }
    }

#pragma unroll
    for (int mat = 0; mat < 3; ++mat) {
        floatx4 acc[2][8];
#pragma unroll
        for (int a = 0; a < 2; ++a)
#pragma unroll
            for (int b = 0; b < 8; ++b)
                acc[a][b] = (floatx4){0.f, 0.f, 0.f, 0.f};
#pragma unroll
        for (int ks = 0; ks < 4; ++ks) {
#pragma unroll
            for (int ct = 0; ct < 8; ++ct) {
                shortx8 bfrag = *(const shortx8*)(WT + (size_t)mat * 16384 +
                                                  ((size_t)(ct * 4 + ks) * 64 + lane) * 8);
                acc[0][ct] = __builtin_amdgcn_mfma_f32_16x16x32_bf16(afrag[0][ks], bfrag, acc[0][ct], 0, 0, 0);
                acc[1][ct] = __builtin_amdgcn_mfma_f32_16x16x32_bf16(afrag[1][ks], bfrag, acc[1][ct], 0, 0, 0);
            }
        }
        u16* base = (mat == 0) ? Qb : (mat == 1) ? KVb : (KVb + 128);
        int stride = (mat == 0) ? 128 : 256;
#pragma unroll
        for (int ct = 0; ct < 8; ++ct) {
            int col = ct * 16 + l15;
            float bs = biasWs[mat * 128 + col];
#pragma unroll
            for (int mt = 0; mt < 2; ++mt) {
#pragma unroll
                for (int r = 0; r < 4; ++r) {
                    int row = m0 + mt * 16 + quad * 4 + r;
                    if (row < M)
                        base[(size_t)row * stride + col] = f2bf(acc[mt][ct][r] + bs);
                }
            }
        }
    }
}

// ---------------------------------------------------------------------------
// Pass 2 over edges: scatter ONLY an 8-byte record pr2[pos] = (src, e)
// (pos from atomic cursor = CSR slot); the 32-byte edge-bias payload is
// written SEQUENTIALLY in edge order (EBe) -- no random RMW write traffic.
// ---------------------------------------------------------------------------
__global__ __launch_bounds__(256) void edge_scatter_k(
    const int* __restrict__ ei, const void* __restrict__ ef,
    int* __restrict__ cur,
    const float* __restrict__ WeWs, const float* __restrict__ beWs,
    int2* __restrict__ pr2, float* __restrict__ EBe,
    int E, const int* __restrict__ flags)
{
    __shared__ float sWe[256];
    __shared__ float sbe[8];
    int tid = threadIdx.x;
    sWe[tid] = WeWs[tid];
    if (tid < 8) sbe[tid] = beWs[tid];
    __syncthreads();

    int e = blockIdx.x * 256 + tid;
    if (e >= E) return;
    bool f32 = flags[0] != 0;
    bool i64 = flags[1] != 0;

    int src = i64 ? ei[2 * e]       : ei[e];
    int tgt = i64 ? ei[2 * (E + e)] : ei[E + e];
    int pos = atomicAdd(&cur[tgt], 1);
    pr2[pos] = make_int2(src, e);

    float v[32];
    if (f32) {
        const floatx4* ep = (const floatx4*)((const float*)ef + (size_t)e * 32);
#pragma unroll
        for (int g = 0; g < 8; ++g) {
            floatx4 t = ep[g];
#pragma unroll
            for (int j = 0; j < 4; ++j) v[g * 4 + j] = t[j];
        }
    } else {
        const shortx8* ep = (const shortx8*)((const u16*)ef + (size_t)e * 32);
#pragma unroll
        for (int g = 0; g < 4; ++g) {
            shortx8 t = ep[g];
#pragma unroll
            for (int j = 0; j < 8; ++j) v[g * 8 + j] = bf2f((unsigned short)t[j]);
        }
    }
    float eb[8];
#pragma unroll
    for (int h = 0; h < 8; ++h) eb[h] = sbe[h];
#pragma unroll
    for (int k = 0; k < 32; ++k)
#pragma unroll
        for (int h = 0; h < 8; ++h) eb[h] += v[k] * sWe[k * 8 + h];

    floatx4* op = (floatx4*)(EBe + (size_t)e * 8);   // EDGE order: coalesced
    op[0] = (floatx4){eb[0], eb[1], eb[2], eb[3]};
    op[1] = (floatx4){eb[4], eb[5], eb[6], eb[7]};
}

// ---------------------------------------------------------------------------
// Per-node aggregation: one wave per node, 4 edges in flight, (src,eid)
// pairs prefetched into registers (via shfl), KV gathered as one 512 B
// region per edge, edge bias gathered from edge-ordered EBe.
// Zero atomics, zero LDS.
// ---------------------------------------------------------------------------
__global__ __launch_bounds__(256) void node_agg_k(
    const int2* __restrict__ pr2, const int* __restrict__ rowptr,
    const u16* __restrict__ Qb, const u16* __restrict__ KVb,
    const float* __restrict__ EBe, u16* __restrict__ aggN, int M, int E)
{
    int wave = threadIdx.x >> 6;
    int lane = threadIdx.x & 63;
    int n = blockIdx.x * 4 + wave;
    if (n >= M) return;
    int g = lane >> 4;
    int w = lane & 15;
    int h = w >> 1;

    int beg = rowptr[n], end = rowptr[n + 1];
    int pidx = beg + lane;
    if (pidx >= E) pidx = E - 1;
    int2 pv = pr2[pidx];                       // prefetch up to 64 records

    uint4 qw = ((const uint4*)(Qb + (size_t)n * 128))[w];
    float q0 = bfl(qw.x), q1 = bfh(qw.x), q2 = bfl(qw.y), q3 = bfh(qw.y);
    float q4 = bfl(qw.z), q5 = bfh(qw.z), q6 = bfl(qw.w), q7 = bfh(qw.w);

    float acc[8];
#pragma unroll
    for (int j = 0; j < 8; ++j) acc[j] = 0.f;
    float dsum = 0.f;

    for (int i = beg; i < end; i += 4) {
        int idx = i + g;
        bool valid = idx < end;
        int cidx = valid ? idx : (end - 1);
        int off = cidx - beg;
        int src, eid;
        if (off < 64) {
            src = __shfl(pv.x, off);
            eid = __shfl(pv.y, off);
        } else {
            int2 t = pr2[cidx];
            src = t.x; eid = t.y;
        }
        float eb = EBe[(size_t)eid * 8 + h];
        const uint4* kvp = (const uint4*)(KVb + (size_t)src * 256);
        uint4 kw = kvp[w];
        uint4 vw = kvp[16 + w];
        float part = q0 * bfl(kw.x) + q1 * bfh(kw.x)
                   + q2 * bfl(kw.y) + q3 * bfh(kw.y)
                   + q4 * bfl(kw.z) + q5 * bfh(kw.z)
                   + q6 * bfl(kw.w) + q7 * bfh(kw.w);
        part += __shfl_xor(part, 1);
        float p = valid ? __expf(part * 0.25f + eb) : 0.f;
        dsum += p;
        acc[0] += p * bfl(vw.x); acc[1] += p * bfh(vw.x);
        acc[2] += p * bfl(vw.y); acc[3] += p * bfh(vw.y);
        acc[4] += p * bfl(vw.z); acc[5] += p * bfh(vw.z);
        acc[6] += p * bfl(vw.w); acc[7] += p * bfh(vw.w);
    }

    dsum += __shfl_xor(dsum, 16);
    dsum += __shfl_xor(dsum, 32);
#pragma unroll
    for (int j = 0; j < 8; ++j) {
        acc[j] += __shfl_xor(acc[j], 16);
        acc[j] += __shfl_xor(acc[j], 32);
    }
    if (g == 0) {
        float inv = 1.0f / (dsum + 1e-10f);
        uint4 o;
        o.x = (u32)f2bf(acc[0] * inv) | ((u32)f2bf(acc[1] * inv) << 16);
        o.y = (u32)f2bf(acc[2] * inv) | ((u32)f2bf(acc[3] * inv) << 16);
        o.z = (u32)f2bf(acc[4] * inv) | ((u32)f2bf(acc[5] * inv) << 16);
        o.w = (u32)f2bf(acc[6] * inv) | ((u32)f2bf(acc[7] * inv) << 16);
        ((uint4*)(aggN + (size_t)n * 128))[w] = o;
    }
}

// ---------------------------------------------------------------------------
// Output GEMM: C = aggN(bf16) @ Wo + bo, out fp32/bf16 per flags[0].
// ---------------------------------------------------------------------------
__global__ __launch_bounds__(256) void out_gemm_k(
    const u16* __restrict__ A, int M,
    const u16* __restrict__ WT, const float* __restrict__ bias,
    void* __restrict__ out, const int* __restrict__ flags)
{
    bool oF32 = flags[0] != 0;
    int lane = threadIdx.x & 63;
    int wave = threadIdx.x >> 6;
    int quad = lane >> 4;
    int l15  = lane & 15;
    int m0   = blockIdx.x * 128 + wave * 32;

    floatx4 acc[2][8];
#pragma unroll
    for (int a = 0; a < 2; ++a)
#pragma unroll
        for (int b = 0; b < 8; ++b)
            acc[a][b] = (floatx4){0.f, 0.f, 0.f, 0.f};

#pragma unroll
    for (int ks = 0; ks < 4; ++ks) {
        shortx8 afrag[2];
#pragma unroll
        for (int mt = 0; mt < 2; ++mt) {
            int row = m0 + mt * 16 + l15;
            row = row < M ? row : M - 1;
            afrag[mt] = *(const shortx8*)(A + (size_t)row * 128 + ks * 32 + quad * 8);
        }
#pragma unroll
        for (int ct = 0; ct < 8; ++ct) {
            shortx8 bfrag = *(const shortx8*)(WT + ((size_t)(ct * 4 + ks) * 64 + lane) * 8);
            acc[0][ct] = __builtin_amdgcn_mfma_f32_16x16x32_bf16(afrag[0], bfrag, acc[0][ct], 0, 0, 0);
            acc[1][ct] = __builtin_amdgcn_mfma_f32_16x16x32_bf16(afrag[1], bfrag, acc[1][ct], 0, 0, 0);
        }
    }

#pragma unroll
    for (int ct = 0; ct < 8; ++ct) {
        int col = ct * 16 + l15;
        float bs = bias[col];
#pragma unroll
        for (int mt = 0; mt < 2; ++mt) {
#pragma unroll
            for (int r = 0; r < 4; ++r) {
                int row = m0 + mt * 16 + quad * 4 + r;
                if (row < M) {
                    float v = acc[mt][ct][r] + bs;
                    if (oF32) ((float*)out)[(size_t)row * 128 + col] = v;
                    else      ((u16*)out)[(size_t)row * 128 + col] = f2bf(v);
                }
            }
        }
    }
}

extern "C" void kernel_launch(void* const* d_in, const int* in_sizes, int n_in,
                              void* d_out, int out_size, void* d_ws, size_t ws_size,
                              hipStream_t stream)
{
    const void* nf = d_in[0];
    const int*  ei = (const int*)d_in[1];
    const void* ef = d_in[2];
    const void* Wq = d_in[3];  const void* bq = d_in[4];
    const void* Wk = d_in[5];  const void* bk = d_in[6];
    const void* Wv = d_in[7];  const void* bv = d_in[8];
    const void* We = d_in[9];  const void* be = d_in[10];
    const void* Wo = d_in[11]; const void* bo = d_in[12];

    int M = in_sizes[0] / 128;   // 50000
    int E = in_sizes[1] / 2;     // 800000
    int nb = (M + 255) / 256;    // 196 <= 256, fits scan2's one block

    // ---- workspace layout (same total size as previous version) ----
    char* ws = (char*)d_ws;
    int*   flags  = (int*)(ws + 0);
    float* biasWs = (float*)(ws + 256);
    float* WeWs   = (float*)(ws + 2304);
    float* beWs   = (float*)(ws + 3328);
    u16*   WT     = (u16*)(ws + 4096);                  // 131072 B
    size_t O1 = 4096 + 131072;
    size_t qrow  = (size_t)M * 128 * 2;                 // Qb bytes
    size_t kvrow = (size_t)M * 256 * 2;                 // KVb bytes (K|V interleaved)
    u16* Qb  = (u16*)(ws + O1);
    u16* KVb = (u16*)(ws + O1 + qrow);
    size_t O2 = O1 + qrow + kvrow;
    float* EBe = (float*)(ws + O2);                     // E*8 fp32, EDGE order
    size_t O3 = O2 + (size_t)E * 8 * 4;
    int2* pr2   = (int2*)(ws + O3);                     // E records (src, eid)
    int* deg    = (int*)(pr2 + E);                      // M
    int* incl   = deg + M;                              // M (becomes cur in scan3)
    int* rowptr = incl + M;                             // M+1
    int* bsum   = rowptr + M + 1;                       // 256
    int* boff   = bsum + 256;                           // 256
    u16* aggN   = Qb;   // safe alias: wave n reads Qb[n] before writing aggN[n]

    detect_zero_k<<<1 + nb, 256, 0, stream>>>((const u16*)nf, ei, flags, deg, M);
    prep_k<<<33, 256, 0, stream>>>(Wq, Wk, Wv, Wo, bq, bk, bv, bo, We, be,
                                   flags, WT, biasWs, WeWs, beWs);

    int eblocks = (E + 255) / 256;
    hist_k<<<eblocks, 256, 0, stream>>>(ei, deg, E, flags);
    scan1_k<<<nb, 256, 0, stream>>>(deg, incl, bsum, M);
    scan2_k<<<1, 256, 0, stream>>>(bsum, boff, nb);
    scan3_k<<<nb, 256, 0, stream>>>(incl, boff, deg, rowptr, M);

    int gblocks = (M + 127) / 128;
    qkv_gemm_k<<<gblocks, 256, 0, stream>>>(nf, M, WT, biasWs, Qb, KVb, flags);

    edge_scatter_k<<<eblocks, 256, 0, stream>>>(ei, ef, incl /*cur*/, WeWs, beWs,
                                                pr2, EBe, E, flags);

    node_agg_k<<<(M + 3) / 4, 256, 0, stream>>>(pr2, rowptr, Qb, KVb, EBe, aggN, M, E);

    out_gemm_k<<<gblocks, 256, 0, stream>>>(aggN, M, WT + 3 * 16384, biasWs + 384, d_out, flags);
}

// Round 2
// 443.117 us; speedup vs baseline: 1.0512x; 1.0512x over previous
//
#include <hip/hip_runtime.h>

typedef __attribute__((ext_vector_type(8))) short shortx8;
typedef __attribute__((ext_vector_type(4))) float floatx4;
typedef unsigned short u16;
typedef unsigned int u32;

__device__ __forceinline__ float bf2f(unsigned short u) {
    union { unsigned int i; float f; } v; v.i = ((unsigned int)u) << 16; return v.f;
}
__device__ __forceinline__ float bfl(u32 u) {
    union { u32 i; float f; } v; v.i = u << 16; return v.f;
}
__device__ __forceinline__ float bfh(u32 u) {
    union { u32 i; float f; } v; v.i = u & 0xFFFF0000u; return v.f;
}
__device__ __forceinline__ unsigned short f2bf(float f) {
    union { float f; unsigned int i; } v; v.f = f;
    unsigned int x = v.i;
    unsigned int r = x + 0x7FFFu + ((x >> 16) & 1u);
    return (unsigned short)(r >> 16);
}
__device__ __forceinline__ float ldf(const void* p, int i, bool f32) {
    return f32 ? ((const float*)p)[i] : bf2f(((const u16*)p)[i]);
}

// ---------------------------------------------------------------------------
// Block 0: storage-format detection (flags[0]: floats fp32; flags[1]: idx
// int64). Blocks 1..: zero the degree array.
// ---------------------------------------------------------------------------
__global__ __launch_bounds__(256) void detect_zero_k(
    const u16* __restrict__ nf, const int* __restrict__ ei,
    int* __restrict__ flags, int* __restrict__ deg, int M)
{
    int tid = threadIdx.x;
    if (blockIdx.x != 0) {
        int i = (blockIdx.x - 1) * 256 + tid;
        if (i < M) deg[i] = 0;
        return;
    }
    __shared__ int cnt[2];
    if (tid < 2) cnt[tid] = 0;
    __syncthreads();
    int c0 = 0;
    for (int i = tid; i < 65536; i += 256) {
        u16 v = nf[i];
        if ((v & 0x7F80u) == 0x7F80u) c0++;
    }
    int c1 = 0;
    for (int i = tid; i < 4096; i += 256) {
        if (ei[2 * i + 1] != 0) c1++;
    }
    atomicAdd(&cnt[0], c0);
    atomicAdd(&cnt[1], c1);
    __syncthreads();
    if (tid == 0) {
        flags[0] = (cnt[0] > 8) ? 1 : 0;
        flags[1] = (cnt[1] < 100) ? 1 : 0;
    }
}

// ---------------------------------------------------------------------------
// Prep: W -> MFMA B-fragment order (bf16); biases/We/be -> fp32 workspace.
// ---------------------------------------------------------------------------
__global__ __launch_bounds__(256) void prep_k(
    const void* __restrict__ W0, const void* __restrict__ W1,
    const void* __restrict__ W2, const void* __restrict__ W3,
    const void* __restrict__ b0, const void* __restrict__ b1,
    const void* __restrict__ b2, const void* __restrict__ b3,
    const void* __restrict__ We, const void* __restrict__ be,
    const int* __restrict__ flags,
    u16* __restrict__ WT, float* __restrict__ biasWs,
    float* __restrict__ WeWs, float* __restrict__ beWs)
{
    bool f32 = flags[0] != 0;
    int tid = threadIdx.x;
    if (blockIdx.x < 32) {
        int t = blockIdx.x * 256 + tid;
        int mat  = t >> 11;
        int r    = t & 2047;
        int lane = r & 63;
        int ks   = (r >> 6) & 3;
        int ct   = r >> 8;
        const void* W = (mat == 0) ? W0 : (mat == 1) ? W1 : (mat == 2) ? W2 : W3;
        int k0  = ks * 32 + (lane >> 4) * 8;
        int col = ct * 16 + (lane & 15);
        u16 tmp[8];
#pragma unroll
        for (int j = 0; j < 8; ++j) {
            int off = (k0 + j) * 128 + col;
            tmp[j] = f32 ? f2bf(((const float*)W)[off]) : ((const u16*)W)[off];
        }
        *(shortx8*)(WT + (size_t)t * 8) = *(const shortx8*)tmp;
    } else {
        if (tid < 128) {
            biasWs[0 * 128 + tid] = ldf(b0, tid, f32);
            biasWs[1 * 128 + tid] = ldf(b1, tid, f32);
            biasWs[2 * 128 + tid] = ldf(b2, tid, f32);
            biasWs[3 * 128 + tid] = ldf(b3, tid, f32);
        }
        WeWs[tid] = ldf(We, tid, f32);
        if (tid < 8) beWs[tid] = ldf(be, tid, f32);
    }
}

// ---------------------------------------------------------------------------
// Pass 1 over edges, FUSED: degree histogram (whose atomic return value IS
// the CSR rank -> rank[e], sequential write) + edge-bias projection EBe in
// EDGE order (sequential write). The big ef stream rides under the atomics.
// ---------------------------------------------------------------------------
__global__ __launch_bounds__(256) void hist_ebias_k(
    const int* __restrict__ ei, const void* __restrict__ ef,
    int* __restrict__ deg, int* __restrict__ rank,
    const float* __restrict__ WeWs, const float* __restrict__ beWs,
    float* __restrict__ EBe, int E, const int* __restrict__ flags)
{
    __shared__ float sWe[256];
    __shared__ float sbe[8];
    int tid = threadIdx.x;
    sWe[tid] = WeWs[tid];
    if (tid < 8) sbe[tid] = beWs[tid];
    __syncthreads();

    int e = blockIdx.x * 256 + tid;
    if (e >= E) return;
    bool f32 = flags[0] != 0;
    int tgt = flags[1] ? ei[2 * (E + e)] : ei[E + e];
    rank[e] = atomicAdd(&deg[tgt], 1);

    float v[32];
    if (f32) {
        const floatx4* ep = (const floatx4*)((const float*)ef + (size_t)e * 32);
#pragma unroll
        for (int g = 0; g < 8; ++g) {
            floatx4 t = ep[g];
#pragma unroll
            for (int j = 0; j < 4; ++j) v[g * 4 + j] = t[j];
        }
    } else {
        const shortx8* ep = (const shortx8*)((const u16*)ef + (size_t)e * 32);
#pragma unroll
        for (int g = 0; g < 4; ++g) {
            shortx8 t = ep[g];
#pragma unroll
            for (int j = 0; j < 8; ++j) v[g * 8 + j] = bf2f((unsigned short)t[j]);
        }
    }
    float eb[8];
#pragma unroll
    for (int h = 0; h < 8; ++h) eb[h] = sbe[h];
#pragma unroll
    for (int k = 0; k < 32; ++k)
#pragma unroll
        for (int h = 0; h < 8; ++h) eb[h] += v[k] * sWe[k * 8 + h];

    floatx4* op = (floatx4*)(EBe + (size_t)e * 8);   // EDGE order: coalesced
    op[0] = (floatx4){eb[0], eb[1], eb[2], eb[3]};
    op[1] = (floatx4){eb[4], eb[5], eb[6], eb[7]};
}

// ---------------------------------------------------------------------------
// Parallel scan (3 tiny kernels): deg -> rowptr (exclusive).
// ---------------------------------------------------------------------------
__global__ __launch_bounds__(256) void scan1_k(
    const int* __restrict__ deg, int* __restrict__ incl, int* __restrict__ bsum, int M)
{
    __shared__ int s[256];
    int tid = threadIdx.x;
    int i = blockIdx.x * 256 + tid;
    int v = (i < M) ? deg[i] : 0;
    s[tid] = v;
    __syncthreads();
#pragma unroll
    for (int off = 1; off < 256; off <<= 1) {
        int t = (tid >= off) ? s[tid - off] : 0;
        __syncthreads();
        s[tid] += t;
        __syncthreads();
    }
    if (i < M) incl[i] = s[tid];
    if (tid == 255) bsum[blockIdx.x] = s[255];
}

__global__ __launch_bounds__(256) void scan2_k(
    const int* __restrict__ bsum, int* __restrict__ boff, int nb)
{
    __shared__ int s[256];
    int tid = threadIdx.x;
    int v = (tid < nb) ? bsum[tid] : 0;
    s[tid] = v;
    __syncthreads();
#pragma unroll
    for (int off = 1; off < 256; off <<= 1) {
        int t = (tid >= off) ? s[tid - off] : 0;
        __syncthreads();
        s[tid] += t;
        __syncthreads();
    }
    if (tid < nb) boff[tid] = s[tid] - v;   // exclusive
}

__global__ __launch_bounds__(256) void scan3_k(
    const int* __restrict__ incl, const int* __restrict__ boff,
    int* __restrict__ rowptr, int M)
{
    int i = blockIdx.x * 256 + threadIdx.x;
    if (i >= M) return;
    rowptr[i + 1] = incl[i] + boff[i >> 8];
    if (i == 0) rowptr[0] = 0;
}

// ---------------------------------------------------------------------------
// Fused QKV GEMM: A fragments loaded once, 3 weight matrices applied.
// Q -> Qb (stride 128); K,V -> interleaved KVb (node n: [K row | V row],
// 512 B per node) so node_agg gathers ONE contiguous region per edge.
// ---------------------------------------------------------------------------
__global__ __launch_bounds__(256) void qkv_gemm_k(
    const void* __restrict__ A, int M,
    const u16* __restrict__ WT, const float* __restrict__ biasWs,
    u16* __restrict__ Qb, u16* __restrict__ KVb,
    const int* __restrict__ flags)
{
    bool aF32 = flags[0] != 0;
    int lane = threadIdx.x & 63;
    int wave = threadIdx.x >> 6;
    int quad = lane >> 4;
    int l15  = lane & 15;
    int m0   = blockIdx.x * 128 + wave * 32;

    shortx8 afrag[2][4];
#pragma unroll
    for (int mt = 0; mt < 2; ++mt) {
        int row = m0 + mt * 16 + l15;
        row = row < M ? row : M - 1;
#pragma unroll
        for (int ks = 0; ks < 4; ++ks) {
            size_t base = (size_t)row * 128 + ks * 32 + quad * 8;
            if (aF32) {
                const floatx4* ap = (const floatx4*)((const float*)A + base);
                floatx4 f0 = ap[0], f1 = ap[1];
                u16 tmp[8];
#pragma unroll
                for (int j = 0; j < 4; ++j) { tmp[j] = f2bf(f0[j]); tmp[4 + j] = f2bf(f1[j]); }
                afrag[mt][ks] = *(const shortx8*)tmp;
            } else {
                afrag[mt][ks] = *(const shortx8*)((const u16*)A + base);
            }
        }
    }

#pragma unroll
    for (int mat = 0; mat < 3; ++mat) {
        floatx4 acc[2][8];
#pragma unroll
        for (int a = 0; a < 2; ++a)
#pragma unroll
            for (int b = 0; b < 8; ++b)
                acc[a][b] = (floatx4){0.f, 0.f, 0.f, 0.f};
#pragma unroll
        for (int ks = 0; ks < 4; ++ks) {
#pragma unroll
            for (int ct = 0; ct < 8; ++ct) {
                shortx8 bfrag = *(const shortx8*)(WT + (size_t)mat * 16384 +
                                                  ((size_t)(ct * 4 + ks) * 64 + lane) * 8);
                acc[0][ct] = __builtin_amdgcn_mfma_f32_16x16x32_bf16(afrag[0][ks], bfrag, acc[0][ct], 0, 0, 0);
                acc[1][ct] = __builtin_amdgcn_mfma_f32_16x16x32_bf16(afrag[1][ks], bfrag, acc[1][ct], 0, 0, 0);
            }
        }
        u16* base = (mat == 0) ? Qb : (mat == 1) ? KVb : (KVb + 128);
        int stride = (mat == 0) ? 128 : 256;
#pragma unroll
        for (int ct = 0; ct < 8; ++ct) {
            int col = ct * 16 + l15;
            float bs = biasWs[mat * 128 + col];
#pragma unroll
            for (int mt = 0; mt < 2; ++mt) {
#pragma unroll
                for (int r = 0; r < 4; ++r) {
                    int row = m0 + mt * 16 + quad * 4 + r;
                    if (row < M)
                        base[(size_t)row * stride + col] = f2bf(acc[mt][ct][r] + bs);
                }
            }
        }
    }
}

// ---------------------------------------------------------------------------
// Pass 2 over edges: ZERO atomics. pos = rowptr[tgt] + rank[e];
// scatter only the 8-byte record pr2[pos] = (src, e).
// ---------------------------------------------------------------------------
__global__ __launch_bounds__(256) void scatter_k(
    const int* __restrict__ ei, const int* __restrict__ rank,
    const int* __restrict__ rowptr, int2* __restrict__ pr2,
    int E, const int* __restrict__ flags)
{
    int e = blockIdx.x * 256 + threadIdx.x;
    if (e >= E) return;
    bool i64 = flags[1] != 0;
    int src = i64 ? ei[2 * e]       : ei[e];
    int tgt = i64 ? ei[2 * (E + e)] : ei[E + e];
    pr2[rowptr[tgt] + rank[e]] = make_int2(src, e);
}

// ---------------------------------------------------------------------------
// Per-node aggregation: one wave per node, 8 edges in flight (2x unrolled),
// (src,eid) pairs prefetched into registers (via shfl), KV gathered as one
// 512 B region per edge, edge bias gathered from edge-ordered EBe.
// Zero atomics, zero LDS.
// ---------------------------------------------------------------------------
__global__ __launch_bounds__(256) void node_agg_k(
    const int2* __restrict__ pr2, const int* __restrict__ rowptr,
    const u16* __restrict__ Qb, const u16* __restrict__ KVb,
    const float* __restrict__ EBe, u16* __restrict__ aggN, int M, int E)
{
    int wave = threadIdx.x >> 6;
    int lane = threadIdx.x & 63;
    int n = blockIdx.x * 4 + wave;
    if (n >= M) return;
    int g = lane >> 4;
    int w = lane & 15;
    int h = w >> 1;

    int beg = rowptr[n], end = rowptr[n + 1];
    int pidx = beg + lane;
    if (pidx >= E) pidx = E - 1;
    int2 pv = pr2[pidx];                       // prefetch up to 64 records

    uint4 qw = ((const uint4*)(Qb + (size_t)n * 128))[w];
    float q0 = bfl(qw.x), q1 = bfh(qw.x), q2 = bfl(qw.y), q3 = bfh(qw.y);
    float q4 = bfl(qw.z), q5 = bfh(qw.z), q6 = bfl(qw.w), q7 = bfh(qw.w);

    float acc[8];
#pragma unroll
    for (int j = 0; j < 8; ++j) acc[j] = 0.f;
    float dsum = 0.f;

    for (int i = beg; i < end; i += 8) {
        int idxA = i + g;
        int idxB = i + 4 + g;
        bool vA = idxA < end;
        bool vB = idxB < end;
        int cA = vA ? idxA : (end - 1);
        int cB = vB ? idxB : (end - 1);
        int offA = cA - beg;
        int offB = cB - beg;
        int srcA, eidA, srcB, eidB;
        if (offA < 64) { srcA = __shfl(pv.x, offA); eidA = __shfl(pv.y, offA); }
        else           { int2 t = pr2[cA]; srcA = t.x; eidA = t.y; }
        if (offB < 64) { srcB = __shfl(pv.x, offB); eidB = __shfl(pv.y, offB); }
        else           { int2 t = pr2[cB]; srcB = t.x; eidB = t.y; }

        const uint4* kpA = (const uint4*)(KVb + (size_t)srcA * 256);
        const uint4* kpB = (const uint4*)(KVb + (size_t)srcB * 256);
        uint4 kwA = kpA[w];
        uint4 kwB = kpB[w];
        uint4 vwA = kpA[16 + w];
        uint4 vwB = kpB[16 + w];
        float ebA = EBe[(size_t)eidA * 8 + h];
        float ebB = EBe[(size_t)eidB * 8 + h];

        float partA = q0 * bfl(kwA.x) + q1 * bfh(kwA.x)
                    + q2 * bfl(kwA.y) + q3 * bfh(kwA.y)
                    + q4 * bfl(kwA.z) + q5 * bfh(kwA.z)
                    + q6 * bfl(kwA.w) + q7 * bfh(kwA.w);
        float partB = q0 * bfl(kwB.x) + q1 * bfh(kwB.x)
                    + q2 * bfl(kwB.y) + q3 * bfh(kwB.y)
                    + q4 * bfl(kwB.z) + q5 * bfh(kwB.z)
                    + q6 * bfl(kwB.w) + q7 * bfh(kwB.w);
        partA += __shfl_xor(partA, 1);
        partB += __shfl_xor(partB, 1);
        float pA = vA ? __expf(partA * 0.25f + ebA) : 0.f;
        float pB = vB ? __expf(partB * 0.25f + ebB) : 0.f;
        dsum += pA + pB;
        acc[0] += pA * bfl(vwA.x) + pB * bfl(vwB.x);
        acc[1] += pA * bfh(vwA.x) + pB * bfh(vwB.x);
        acc[2] += pA * bfl(vwA.y) + pB * bfl(vwB.y);
        acc[3] += pA * bfh(vwA.y) + pB * bfh(vwB.y);
        acc[4] += pA * bfl(vwA.z) + pB * bfl(vwB.z);
        acc[5] += pA * bfh(vwA.z) + pB * bfh(vwB.z);
        acc[6] += pA * bfl(vwA.w) + pB * bfl(vwB.w);
        acc[7] += pA * bfh(vwA.w) + pB * bfh(vwB.w);
    }

    dsum += __shfl_xor(dsum, 16);
    dsum += __shfl_xor(dsum, 32);
#pragma unroll
    for (int j = 0; j < 8; ++j) {
        acc[j] += __shfl_xor(acc[j], 16);
        acc[j] += __shfl_xor(acc[j], 32);
    }
    if (g == 0) {
        float inv = 1.0f / (dsum + 1e-10f);
        uint4 o;
        o.x = (u32)f2bf(acc[0] * inv) | ((u32)f2bf(acc[1] * inv) << 16);
        o.y = (u32)f2bf(acc[2] * inv) | ((u32)f2bf(acc[3] * inv) << 16);
        o.z = (u32)f2bf(acc[4] * inv) | ((u32)f2bf(acc[5] * inv) << 16);
        o.w = (u32)f2bf(acc[6] * inv) | ((u32)f2bf(acc[7] * inv) << 16);
        ((uint4*)(aggN + (size_t)n * 128))[w] = o;
    }
}

// ---------------------------------------------------------------------------
// Output GEMM: C = aggN(bf16) @ Wo + bo, out fp32/bf16 per flags[0].
// ---------------------------------------------------------------------------
__global__ __launch_bounds__(256) void out_gemm_k(
    const u16* __restrict__ A, int M,
    const u16* __restrict__ WT, const float* __restrict__ bias,
    void* __restrict__ out, const int* __restrict__ flags)
{
    bool oF32 = flags[0] != 0;
    int lane = threadIdx.x & 63;
    int wave = threadIdx.x >> 6;
    int quad = lane >> 4;
    int l15  = lane & 15;
    int m0   = blockIdx.x * 128 + wave * 32;

    floatx4 acc[2][8];
#pragma unroll
    for (int a = 0; a < 2; ++a)
#pragma unroll
        for (int b = 0; b < 8; ++b)
            acc[a][b] = (floatx4){0.f, 0.f, 0.f, 0.f};

#pragma unroll
    for (int ks = 0; ks < 4; ++ks) {
        shortx8 afrag[2];
#pragma unroll
        for (int mt = 0; mt < 2; ++mt) {
            int row = m0 + mt * 16 + l15;
            row = row < M ? row : M - 1;
            afrag[mt] = *(const shortx8*)(A + (size_t)row * 128 + ks * 32 + quad * 8);
        }
#pragma unroll
        for (int ct = 0; ct < 8; ++ct) {
            shortx8 bfrag = *(const shortx8*)(WT + ((size_t)(ct * 4 + ks) * 64 + lane) * 8);
            acc[0][ct] = __builtin_amdgcn_mfma_f32_16x16x32_bf16(afrag[0], bfrag, acc[0][ct], 0, 0, 0);
            acc[1][ct] = __builtin_amdgcn_mfma_f32_16x16x32_bf16(afrag[1], bfrag, acc[1][ct], 0, 0, 0);
        }
    }

#pragma unroll
    for (int ct = 0; ct < 8; ++ct) {
        int col = ct * 16 + l15;
        float bs = bias[col];
#pragma unroll
        for (int mt = 0; mt < 2; ++mt) {
#pragma unroll
            for (int r = 0; r < 4; ++r) {
                int row = m0 + mt * 16 + quad * 4 + r;
                if (row < M) {
                    float v = acc[mt][ct][r] + bs;
                    if (oF32) ((float*)out)[(size_t)row * 128 + col] = v;
                    else      ((u16*)out)[(size_t)row * 128 + col] = f2bf(v);
                }
            }
        }
    }
}

extern "C" void kernel_launch(void* const* d_in, const int* in_sizes, int n_in,
                              void* d_out, int out_size, void* d_ws, size_t ws_size,
                              hipStream_t stream)
{
    const void* nf = d_in[0];
    const int*  ei = (const int*)d_in[1];
    const void* ef = d_in[2];
    const void* Wq = d_in[3];  const void* bq = d_in[4];
    const void* Wk = d_in[5];  const void* bk = d_in[6];
    const void* Wv = d_in[7];  const void* bv = d_in[8];
    const void* We = d_in[9];  const void* be = d_in[10];
    const void* Wo = d_in[11]; const void* bo = d_in[12];

    int M = in_sizes[0] / 128;   // 50000
    int E = in_sizes[1] / 2;     // 800000
    int nb = (M + 255) / 256;    // 196 <= 256, fits scan2's one block

    // ---- workspace layout ----
    char* ws = (char*)d_ws;
    int*   flags  = (int*)(ws + 0);
    float* biasWs = (float*)(ws + 256);
    float* WeWs   = (float*)(ws + 2304);
    float* beWs   = (float*)(ws + 3328);
    u16*   WT     = (u16*)(ws + 4096);                  // 131072 B
    size_t O1 = 4096 + 131072;
    size_t qrow  = (size_t)M * 128 * 2;                 // Qb bytes
    size_t kvrow = (size_t)M * 256 * 2;                 // KVb bytes (K|V interleaved)
    u16* Qb  = (u16*)(ws + O1);
    u16* KVb = (u16*)(ws + O1 + qrow);
    size_t O2 = O1 + qrow + kvrow;
    float* EBe = (float*)(ws + O2);                     // E*8 fp32, EDGE order
    size_t O3 = O2 + (size_t)E * 8 * 4;
    int2* pr2   = (int2*)(ws + O3);                     // E records (src, eid)
    int* rank   = (int*)(pr2 + E);                      // E
    int* deg    = rank + E;                             // M
    int* incl   = deg + M;                              // M
    int* rowptr = incl + M;                             // M+1
    int* bsum   = rowptr + M + 1;                       // 256
    int* boff   = bsum + 256;                           // 256
    u16* aggN   = Qb;   // safe alias: wave n reads Qb[n] before writing aggN[n]

    detect_zero_k<<<1 + nb, 256, 0, stream>>>((const u16*)nf, ei, flags, deg, M);
    prep_k<<<33, 256, 0, stream>>>(Wq, Wk, Wv, Wo, bq, bk, bv, bo, We, be,
                                   flags, WT, biasWs, WeWs, beWs);

    int eblocks = (E + 255) / 256;
    hist_ebias_k<<<eblocks, 256, 0, stream>>>(ei, ef, deg, rank, WeWs, beWs,
                                              EBe, E, flags);
    scan1_k<<<nb, 256, 0, stream>>>(deg, incl, bsum, M);
    scan2_k<<<1, 256, 0, stream>>>(bsum, boff, nb);
    scan3_k<<<nb, 256, 0, stream>>>(incl, boff, rowptr, M);

    int gblocks = (M + 127) / 128;
    qkv_gemm_k<<<gblocks, 256, 0, stream>>>(nf, M, WT, biasWs, Qb, KVb, flags);

    scatter_k<<<eblocks, 256, 0, stream>>>(ei, rank, rowptr, pr2, E, flags);

    node_agg_k<<<(M + 3) / 4, 256, 0, stream>>>(pr2, rowptr, Qb, KVb, EBe, aggN, M, E);

    out_gemm_k<<<gblocks, 256, 0, stream>>>(aggN, M, WT + 3 * 16384, biasWs + 384, d_out, flags);
}

// Round 3
// 383.628 us; speedup vs baseline: 1.2143x; 1.1551x over previous
//
#include <hip/hip_runtime.h>

typedef __attribute__((ext_vector_type(8))) short shortx8;
typedef __attribute__((ext_vector_type(4))) float floatx4;
typedef unsigned short u16;
typedef unsigned int u32;

__device__ __forceinline__ float bf2f(unsigned short u) {
    union { unsigned int i; float f; } v; v.i = ((unsigned int)u) << 16; return v.f;
}
__device__ __forceinline__ float bfl(u32 u) {
    union { u32 i; float f; } v; v.i = u << 16; return v.f;
}
__device__ __forceinline__ float bfh(u32 u) {
    union { u32 i; float f; } v; v.i = u & 0xFFFF0000u; return v.f;
}
__device__ __forceinline__ unsigned short f2bf(float f) {
    union { float f; unsigned int i; } v; v.f = f;
    unsigned int x = v.i;
    unsigned int r = x + 0x7FFFu + ((x >> 16) & 1u);
    return (unsigned short)(r >> 16);
}
__device__ __forceinline__ u32 pack2bf(float a, float b) {
    return (u32)f2bf(a) | ((u32)f2bf(b) << 16);
}
__device__ __forceinline__ float ldf(const void* p, int i, bool f32) {
    return f32 ? ((const float*)p)[i] : bf2f(((const u16*)p)[i]);
}

// ---------------------------------------------------------------------------
// Merged detect + prep + deg-zero. Each prep block SELF-detects storage
// format (8K nf samples for fp32-vs-bf16; block 32 also samples ei for
// int64-vs-int32 and publishes global flags for later kernels).
//   blocks 0..31 : W -> MFMA B-fragment order (bf16)
//   block  32    : biases/We/be -> fp32 workspace + global flags
//   blocks 33..  : zero deg
// ---------------------------------------------------------------------------
__global__ __launch_bounds__(256) void prep_all_k(
    const u16* __restrict__ nf, const int* __restrict__ ei,
    const void* __restrict__ W0, const void* __restrict__ W1,
    const void* __restrict__ W2, const void* __restrict__ W3,
    const void* __restrict__ b0, const void* __restrict__ b1,
    const void* __restrict__ b2, const void* __restrict__ b3,
    const void* __restrict__ We, const void* __restrict__ be,
    int* __restrict__ flags, int* __restrict__ deg,
    u16* __restrict__ WT, float* __restrict__ biasWs,
    float* __restrict__ WeWs, float* __restrict__ beWs, int M)
{
    int tid = threadIdx.x;
    int bid = blockIdx.x;
    if (bid >= 33) {
        int i = (bid - 33) * 256 + tid;
        if (i < M) deg[i] = 0;
        return;
    }
    __shared__ int cnt[2];
    if (tid < 2) cnt[tid] = 0;
    __syncthreads();
    int c0 = 0;
    for (int i = tid; i < 8192; i += 256) {
        u16 v = nf[i];
        if ((v & 0x7F80u) == 0x7F80u) c0++;
    }
    atomicAdd(&cnt[0], c0);
    if (bid == 32) {
        int c1 = 0;
        for (int i = tid; i < 1024; i += 256) {
            if (ei[2 * i + 1] != 0) c1++;
        }
        atomicAdd(&cnt[1], c1);
    }
    __syncthreads();
    bool f32 = cnt[0] > 6;   // fp32 low-mantissa u16s hit exp=255 ~1/256

    if (bid < 32) {
        int t = bid * 256 + tid;
        int mat  = t >> 11;
        int r    = t & 2047;
        int lane = r & 63;
        int ks   = (r >> 6) & 3;
        int ct   = r >> 8;
        const void* W = (mat == 0) ? W0 : (mat == 1) ? W1 : (mat == 2) ? W2 : W3;
        int k0  = ks * 32 + (lane >> 4) * 8;
        int col = ct * 16 + (lane & 15);
        u16 tmp[8];
#pragma unroll
        for (int j = 0; j < 8; ++j) {
            int off = (k0 + j) * 128 + col;
            tmp[j] = f32 ? f2bf(((const float*)W)[off]) : ((const u16*)W)[off];
        }
        *(shortx8*)(WT + (size_t)t * 8) = *(const shortx8*)tmp;
    } else {
        if (tid == 0) {
            flags[0] = f32 ? 1 : 0;
            flags[1] = (cnt[1] < 100) ? 1 : 0;
        }
        if (tid < 128) {
            biasWs[0 * 128 + tid] = ldf(b0, tid, f32);
            biasWs[1 * 128 + tid] = ldf(b1, tid, f32);
            biasWs[2 * 128 + tid] = ldf(b2, tid, f32);
            biasWs[3 * 128 + tid] = ldf(b3, tid, f32);
        }
        WeWs[tid] = ldf(We, tid, f32);
        if (tid < 8) beWs[tid] = ldf(be, tid, f32);
    }
}

// ---------------------------------------------------------------------------
// Pure target histogram (rank comes later from the atomic cursor).
// ---------------------------------------------------------------------------
__global__ __launch_bounds__(256) void hist_k(
    const int* __restrict__ ei, int* __restrict__ deg,
    int E, const int* __restrict__ flags)
{
    int e = blockIdx.x * 256 + threadIdx.x;
    if (e >= E) return;
    int tgt = flags[1] ? ei[2 * (E + e)] : ei[E + e];
    atomicAdd(&deg[tgt], 1);
}

// ---------------------------------------------------------------------------
// scan1: per-block inclusive scan of deg -> incl, block sums -> bsum.
// ---------------------------------------------------------------------------
__global__ __launch_bounds__(256) void scan1_k(
    const int* __restrict__ deg, int* __restrict__ incl, int* __restrict__ bsum, int M)
{
    __shared__ int s[256];
    int tid = threadIdx.x;
    int i = blockIdx.x * 256 + tid;
    int v = (i < M) ? deg[i] : 0;
    s[tid] = v;
    __syncthreads();
#pragma unroll
    for (int off = 1; off < 256; off <<= 1) {
        int t = (tid >= off) ? s[tid - off] : 0;
        __syncthreads();
        s[tid] += t;
        __syncthreads();
    }
    if (i < M) incl[i] = s[tid];
    if (tid == 255) bsum[blockIdx.x] = s[255];
}

// ---------------------------------------------------------------------------
// scan2+3 merged: every block redundantly scans bsum (<=256 entries) in LDS,
// then rowptr[i+1] = incl[i] + boff, and incl[i] is rewritten IN PLACE to
// rowptr[i] (the scatter cursor).
// ---------------------------------------------------------------------------
__global__ __launch_bounds__(256) void scan23_k(
    const int* __restrict__ bsum, int* __restrict__ incl_cur,
    const int* __restrict__ deg, int* __restrict__ rowptr, int M, int nb)
{
    __shared__ int s[256];
    int tid = threadIdx.x;
    int v = (tid < nb) ? bsum[tid] : 0;
    s[tid] = v;
    __syncthreads();
#pragma unroll
    for (int off = 1; off < 256; off <<= 1) {
        int t = (tid >= off) ? s[tid - off] : 0;
        __syncthreads();
        s[tid] += t;
        __syncthreads();
    }
    int b = blockIdx.x;
    int boffb = (b == 0) ? 0 : s[b - 1];   // exclusive offset of this block
    int i = b * 256 + tid;
    if (i >= M) return;
    int r = incl_cur[i] + boffb;           // inclusive prefix = rowptr[i+1]
    rowptr[i + 1] = r;
    incl_cur[i] = r - deg[i];              // cur[i] = rowptr[i]
    if (i == 0) rowptr[0] = 0;
}

// ---------------------------------------------------------------------------
// FUSED: blocks [0,gblocks) = QKV GEMM; blocks [gblocks,..) = edge scatter.
// Overlaps MFMA-bound GEMM with RMW-stall-bound scatter on the same CUs.
//
// Scatter writes one 32 B record per edge at its CSR slot:
//   word0 = src, word1..4 = eb[8] packed as bf16 pairs, word5..7 = 0.
// 2 records/line -> ~2 RMW writers per line (vs 8 for 8 B records).
// ---------------------------------------------------------------------------
__global__ __launch_bounds__(256) void qkv_scatter_k(
    const void* __restrict__ A, int M,
    const u16* __restrict__ WT, const float* __restrict__ biasWs,
    u16* __restrict__ Qb, u16* __restrict__ KVb,
    const int* __restrict__ ei, const void* __restrict__ ef,
    int* __restrict__ cur,
    const float* __restrict__ WeWs, const float* __restrict__ beWs,
    uint4* __restrict__ rec, int E,
    const int* __restrict__ flags, int gblocks)
{
    __shared__ float sWe[256];
    __shared__ float sbe[8];

    if (blockIdx.x < gblocks) {
        // ---------------- QKV GEMM ----------------
        bool aF32 = flags[0] != 0;
        int lane = threadIdx.x & 63;
        int wave = threadIdx.x >> 6;
        int quad = lane >> 4;
        int l15  = lane & 15;
        int m0   = blockIdx.x * 128 + wave * 32;

        shortx8 afrag[2][4];
#pragma unroll
        for (int mt = 0; mt < 2; ++mt) {
            int row = m0 + mt * 16 + l15;
            row = row < M ? row : M - 1;
#pragma unroll
            for (int ks = 0; ks < 4; ++ks) {
                size_t base = (size_t)row * 128 + ks * 32 + quad * 8;
                if (aF32) {
                    const floatx4* ap = (const floatx4*)((const float*)A + base);
                    floatx4 f0 = ap[0], f1 = ap[1];
                    u16 tmp[8];
#pragma unroll
                    for (int j = 0; j < 4; ++j) { tmp[j] = f2bf(f0[j]); tmp[4 + j] = f2bf(f1[j]); }
                    afrag[mt][ks] = *(const shortx8*)tmp;
                } else {
                    afrag[mt][ks] = *(const shortx8*)((const u16*)A + base);
                }
            }
        }

#pragma unroll
        for (int mat = 0; mat < 3; ++mat) {
            floatx4 acc[2][8];
#pragma unroll
            for (int a = 0; a < 2; ++a)
#pragma unroll
                for (int b = 0; b < 8; ++b)
                    acc[a][b] = (floatx4){0.f, 0.f, 0.f, 0.f};
#pragma unroll
            for (int ks = 0; ks < 4; ++ks) {
#pragma unroll
                for (int ct = 0; ct < 8; ++ct) {
                    shortx8 bfrag = *(const shortx8*)(WT + (size_t)mat * 16384 +
                                                      ((size_t)(ct * 4 + ks) * 64 + lane) * 8);
                    acc[0][ct] = __builtin_amdgcn_mfma_f32_16x16x32_bf16(afrag[0][ks], bfrag, acc[0][ct], 0, 0, 0);
                    acc[1][ct] = __builtin_amdgcn_mfma_f32_16x16x32_bf16(afrag[1][ks], bfrag, acc[1][ct], 0, 0, 0);
                }
            }
            u16* base = (mat == 0) ? Qb : (mat == 1) ? KVb : (KVb + 128);
            int stride = (mat == 0) ? 128 : 256;
#pragma unroll
            for (int ct = 0; ct < 8; ++ct) {
                int col = ct * 16 + l15;
                float bs = biasWs[mat * 128 + col];
#pragma unroll
                for (int mt = 0; mt < 2; ++mt) {
#pragma unroll
                    for (int r = 0; r < 4; ++r) {
                        int row = m0 + mt * 16 + quad * 4 + r;
                        if (row < M)
                            base[(size_t)row * stride + col] = f2bf(acc[mt][ct][r] + bs);
                    }
                }
            }
        }
    } else {
        // ---------------- edge scatter + EB projection ----------------
        int tid = threadIdx.x;
        sWe[tid] = WeWs[tid];
        if (tid < 8) sbe[tid] = beWs[tid];
        __syncthreads();

        int e = (blockIdx.x - gblocks) * 256 + tid;
        if (e >= E) return;
        bool f32 = flags[0] != 0;
        bool i64 = flags[1] != 0;

        int src = i64 ? ei[2 * e]       : ei[e];
        int tgt = i64 ? ei[2 * (E + e)] : ei[E + e];
        int pos = atomicAdd(&cur[tgt], 1);

        float v[32];
        if (f32) {
            const floatx4* ep = (const floatx4*)((const float*)ef + (size_t)e * 32);
#pragma unroll
            for (int g = 0; g < 8; ++g) {
                floatx4 t = ep[g];
#pragma unroll
                for (int j = 0; j < 4; ++j) v[g * 4 + j] = t[j];
            }
        } else {
            const shortx8* ep = (const shortx8*)((const u16*)ef + (size_t)e * 32);
#pragma unroll
            for (int g = 0; g < 4; ++g) {
                shortx8 t = ep[g];
#pragma unroll
                for (int j = 0; j < 8; ++j) v[g * 8 + j] = bf2f((unsigned short)t[j]);
            }
        }
        float eb[8];
#pragma unroll
        for (int h = 0; h < 8; ++h) eb[h] = sbe[h];
#pragma unroll
        for (int k = 0; k < 32; ++k)
#pragma unroll
            for (int h = 0; h < 8; ++h) eb[h] += v[k] * sWe[k * 8 + h];

        uint4 r0, r1;
        r0.x = (u32)src;
        r0.y = pack2bf(eb[0], eb[1]);
        r0.z = pack2bf(eb[2], eb[3]);
        r0.w = pack2bf(eb[4], eb[5]);
        r1.x = pack2bf(eb[6], eb[7]);
        r1.y = 0; r1.z = 0; r1.w = 0;
        rec[(size_t)pos * 2]     = r0;
        rec[(size_t)pos * 2 + 1] = r1;
    }
}

// ---------------------------------------------------------------------------
// Per-node aggregation: one wave per node, 8 edges in flight, records
// (src + eb bf16) prefetched into registers (2 lanes per 32 B record,
// 32 records covered), KV gathered as one 512 B region per edge.
// Zero atomics, zero LDS, no random EB gather.
// ---------------------------------------------------------------------------
__global__ __launch_bounds__(256) void node_agg_k(
    const uint4* __restrict__ rec, const int* __restrict__ rowptr,
    const u16* __restrict__ Qb, const u16* __restrict__ KVb,
    u16* __restrict__ aggN, int M, int E)
{
    int wave = threadIdx.x >> 6;
    int lane = threadIdx.x & 63;
    int n = blockIdx.x * 4 + wave;
    if (n >= M) return;
    int g = lane >> 4;
    int w = lane & 15;
    int h = w >> 1;

    int beg = rowptr[n], end = rowptr[n + 1];
    int ridx = beg + (lane >> 1);
    if (ridx >= E) ridx = E - 1;
    uint4 pv = rec[(size_t)ridx * 2 + (lane & 1)];
    // lane 2j  : words 0-3 of record beg+j = [src, eb01, eb23, eb45]
    // lane 2j+1: words 4-7                 = [eb67, 0, 0, 0]

    uint4 qw = ((const uint4*)(Qb + (size_t)n * 128))[w];
    float q0 = bfl(qw.x), q1 = bfh(qw.x), q2 = bfl(qw.y), q3 = bfh(qw.y);
    float q4 = bfl(qw.z), q5 = bfh(qw.z), q6 = bfl(qw.w), q7 = bfh(qw.w);

    float acc[8];
#pragma unroll
    for (int j = 0; j < 8; ++j) acc[j] = 0.f;
    float dsum = 0.f;

    for (int i = beg; i < end; i += 8) {
        int idxA = i + g;
        int idxB = i + 4 + g;
        bool vA = idxA < end;
        bool vB = idxB < end;
        int cA = vA ? idxA : (end - 1);
        int cB = vB ? idxB : (end - 1);
        int offA = cA - beg;
        int offB = cB - beg;

        int srcA, srcB;
        float ebA, ebB;
        if (offA < 32) {
            srcA = __shfl((int)pv.x, 2 * offA);
            u32 w01 = __shfl((int)pv.y, 2 * offA);
            u32 w23 = __shfl((int)pv.z, 2 * offA);
            u32 w45 = __shfl((int)pv.w, 2 * offA);
            u32 w67 = __shfl((int)pv.x, 2 * offA + 1);
            u32 sel = (h < 2) ? w01 : (h < 4) ? w23 : (h < 6) ? w45 : w67;
            ebA = (h & 1) ? bfh(sel) : bfl(sel);
        } else {
            const u32* rw = (const u32*)(rec + (size_t)cA * 2);
            srcA = (int)rw[0];
            u32 sel = rw[1 + h / 2];
            ebA = (h & 1) ? bfh(sel) : bfl(sel);
        }
        if (offB < 32) {
            srcB = __shfl((int)pv.x, 2 * offB);
            u32 w01 = __shfl((int)pv.y, 2 * offB);
            u32 w23 = __shfl((int)pv.z, 2 * offB);
            u32 w45 = __shfl((int)pv.w, 2 * offB);
            u32 w67 = __shfl((int)pv.x, 2 * offB + 1);
            u32 sel = (h < 2) ? w01 : (h < 4) ? w23 : (h < 6) ? w45 : w67;
            ebB = (h & 1) ? bfh(sel) : bfl(sel);
        } else {
            const u32* rw = (const u32*)(rec + (size_t)cB * 2);
            srcB = (int)rw[0];
            u32 sel = rw[1 + h / 2];
            ebB = (h & 1) ? bfh(sel) : bfl(sel);
        }

        const uint4* kpA = (const uint4*)(KVb + (size_t)srcA * 256);
        const uint4* kpB = (const uint4*)(KVb + (size_t)srcB * 256);
        uint4 kwA = kpA[w];
        uint4 kwB = kpB[w];
        uint4 vwA = kpA[16 + w];
        uint4 vwB = kpB[16 + w];

        float partA = q0 * bfl(kwA.x) + q1 * bfh(kwA.x)
                    + q2 * bfl(kwA.y) + q3 * bfh(kwA.y)
                    + q4 * bfl(kwA.z) + q5 * bfh(kwA.z)
                    + q6 * bfl(kwA.w) + q7 * bfh(kwA.w);
        float partB = q0 * bfl(kwB.x) + q1 * bfh(kwB.x)
                    + q2 * bfl(kwB.y) + q3 * bfh(kwB.y)
                    + q4 * bfl(kwB.z) + q5 * bfh(kwB.z)
                    + q6 * bfl(kwB.w) + q7 * bfh(kwB.w);
        partA += __shfl_xor(partA, 1);
        partB += __shfl_xor(partB, 1);
        float pA = vA ? __expf(partA * 0.25f + ebA) : 0.f;
        float pB = vB ? __expf(partB * 0.25f + ebB) : 0.f;
        dsum += pA + pB;
        acc[0] += pA * bfl(vwA.x) + pB * bfl(vwB.x);
        acc[1] += pA * bfh(vwA.x) + pB * bfh(vwB.x);
        acc[2] += pA * bfl(vwA.y) + pB * bfl(vwB.y);
        acc[3] += pA * bfh(vwA.y) + pB * bfh(vwB.y);
        acc[4] += pA * bfl(vwA.z) + pB * bfl(vwB.z);
        acc[5] += pA * bfh(vwA.z) + pB * bfh(vwB.z);
        acc[6] += pA * bfl(vwA.w) + pB * bfl(vwB.w);
        acc[7] += pA * bfh(vwA.w) + pB * bfh(vwB.w);
    }

    dsum += __shfl_xor(dsum, 16);
    dsum += __shfl_xor(dsum, 32);
#pragma unroll
    for (int j = 0; j < 8; ++j) {
        acc[j] += __shfl_xor(acc[j], 16);
        acc[j] += __shfl_xor(acc[j], 32);
    }
    if (g == 0) {
        float inv = 1.0f / (dsum + 1e-10f);
        uint4 o;
        o.x = (u32)f2bf(acc[0] * inv) | ((u32)f2bf(acc[1] * inv) << 16);
        o.y = (u32)f2bf(acc[2] * inv) | ((u32)f2bf(acc[3] * inv) << 16);
        o.z = (u32)f2bf(acc[4] * inv) | ((u32)f2bf(acc[5] * inv) << 16);
        o.w = (u32)f2bf(acc[6] * inv) | ((u32)f2bf(acc[7] * inv) << 16);
        ((uint4*)(aggN + (size_t)n * 128))[w] = o;
    }
}

// ---------------------------------------------------------------------------
// Output GEMM: C = aggN(bf16) @ Wo + bo, out fp32/bf16 per flags[0].
// ---------------------------------------------------------------------------
__global__ __launch_bounds__(256) void out_gemm_k(
    const u16* __restrict__ A, int M,
    const u16* __restrict__ WT, const float* __restrict__ bias,
    void* __restrict__ out, const int* __restrict__ flags)
{
    bool oF32 = flags[0] != 0;
    int lane = threadIdx.x & 63;
    int wave = threadIdx.x >> 6;
    int quad = lane >> 4;
    int l15  = lane & 15;
    int m0   = blockIdx.x * 128 + wave * 32;

    floatx4 acc[2][8];
#pragma unroll
    for (int a = 0; a < 2; ++a)
#pragma unroll
        for (int b = 0; b < 8; ++b)
            acc[a][b] = (floatx4){0.f, 0.f, 0.f, 0.f};

#pragma unroll
    for (int ks = 0; ks < 4; ++ks) {
        shortx8 afrag[2];
#pragma unroll
        for (int mt = 0; mt < 2; ++mt) {
            int row = m0 + mt * 16 + l15;
            row = row < M ? row : M - 1;
            afrag[mt] = *(const shortx8*)(A + (size_t)row * 128 + ks * 32 + quad * 8);
        }
#pragma unroll
        for (int ct = 0; ct < 8; ++ct) {
            shortx8 bfrag = *(const shortx8*)(WT + ((size_t)(ct * 4 + ks) * 64 + lane) * 8);
            acc[0][ct] = __builtin_amdgcn_mfma_f32_16x16x32_bf16(afrag[0], bfrag, acc[0][ct], 0, 0, 0);
            acc[1][ct] = __builtin_amdgcn_mfma_f32_16x16x32_bf16(afrag[1], bfrag, acc[1][ct], 0, 0, 0);
        }
    }

#pragma unroll
    for (int ct = 0; ct < 8; ++ct) {
        int col = ct * 16 + l15;
        float bs = bias[col];
#pragma unroll
        for (int mt = 0; mt < 2; ++mt) {
#pragma unroll
            for (int r = 0; r < 4; ++r) {
                int row = m0 + mt * 16 + quad * 4 + r;
                if (row < M) {
                    float v = acc[mt][ct][r] + bs;
                    if (oF32) ((float*)out)[(size_t)row * 128 + col] = v;
                    else      ((u16*)out)[(size_t)row * 128 + col] = f2bf(v);
                }
            }
        }
    }
}

extern "C" void kernel_launch(void* const* d_in, const int* in_sizes, int n_in,
                              void* d_out, int out_size, void* d_ws, size_t ws_size,
                              hipStream_t stream)
{
    const void* nf = d_in[0];
    const int*  ei = (const int*)d_in[1];
    const void* ef = d_in[2];
    const void* Wq = d_in[3];  const void* bq = d_in[4];
    const void* Wk = d_in[5];  const void* bk = d_in[6];
    const void* Wv = d_in[7];  const void* bv = d_in[8];
    const void* We = d_in[9];  const void* be = d_in[10];
    const void* Wo = d_in[11]; const void* bo = d_in[12];

    int M = in_sizes[0] / 128;   // 50000
    int E = in_sizes[1] / 2;     // 800000
    int nb = (M + 255) / 256;    // 196 <= 256

    // ---- workspace layout ----
    char* ws = (char*)d_ws;
    int*   flags  = (int*)(ws + 0);
    float* biasWs = (float*)(ws + 256);
    float* WeWs   = (float*)(ws + 2304);
    float* beWs   = (float*)(ws + 3328);
    u16*   WT     = (u16*)(ws + 4096);                  // 131072 B
    size_t O1 = 4096 + 131072;
    size_t qrow  = (size_t)M * 128 * 2;                 // Qb bytes (12.8 MB)
    size_t kvrow = (size_t)M * 256 * 2;                 // KVb bytes (25.6 MB)
    u16* Qb  = (u16*)(ws + O1);
    u16* KVb = (u16*)(ws + O1 + qrow);
    size_t O2 = O1 + qrow + kvrow;
    uint4* rec = (uint4*)(ws + O2);                     // E * 32 B records
    size_t O3 = O2 + (size_t)E * 32;
    int* deg    = (int*)(ws + O3);                      // M
    int* incl   = deg + M;                              // M (becomes cur)
    int* rowptr = incl + M;                             // M+1
    int* bsum   = rowptr + M + 1;                       // 256
    u16* aggN   = Qb;   // safe alias: wave n reads Qb[n] before writing aggN[n]

    prep_all_k<<<33 + nb, 256, 0, stream>>>((const u16*)nf, ei,
                                            Wq, Wk, Wv, Wo, bq, bk, bv, bo, We, be,
                                            flags, deg, WT, biasWs, WeWs, beWs, M);

    int eblocks = (E + 255) / 256;
    hist_k<<<eblocks, 256, 0, stream>>>(ei, deg, E, flags);
    scan1_k<<<nb, 256, 0, stream>>>(deg, incl, bsum, M);
    scan23_k<<<nb, 256, 0, stream>>>(bsum, incl, deg, rowptr, M, nb);

    int gblocks = (M + 127) / 128;
    qkv_scatter_k<<<gblocks + eblocks, 256, 0, stream>>>(
        nf, M, WT, biasWs, Qb, KVb,
        ei, ef, incl /*cur*/, WeWs, beWs, rec, E, flags, gblocks);

    node_agg_k<<<(M + 3) / 4, 256, 0, stream>>>(rec, rowptr, Qb, KVb, aggN, M, E);

    out_gemm_k<<<gblocks, 256, 0, stream>>>(aggN, M, WT + 3 * 16384, biasWs + 384, d_out, flags);
}